// Round 5
// baseline (198.010 us; speedup 1.0000x reference)
//
#include <hip/hip_runtime.h>
#include <math.h>

#define EPS 1e-7f
#define NETS 3
#define HROWP 384                 // padded rows per net per half (325 useful)
#define HG    (HROWP/4)           // 96 groups per net per half
#define GPW   (HG/4)              // 24 groups per wave per net
#define JSTRIDE (NETS*HROWP)      // 1152 floats between j's in sU
#define W2R_F4_TOT (2*NETS*HG*64) // 36864 float4s
#define ZPART_OFF 589824          // bytes: after W2r
#define ZCNT_OFF  2162688         // bytes: after Zpart (384*2*512 floats)

// ---------------------------------------------------------------------------
// K1: head-reduced hyper-weights packed [half][net][g][hid][4rows]; also
// zeroes the per-agent completion counters used by K2's fused epilogue.
// Row layout per (half,net): rows<320: kk_local*64+h (kk = half*5+kk_local);
// rows 320..324: b2 path; 325..383: zero pad.
// col(kk) = kk*256 for kk<9, 2304 for kk==9 (the "+b" einsum term, f'[9]=1).
// ---------------------------------------------------------------------------
__global__ __launch_bounds__(256) void prep_w2r(
    const float* __restrict__ W2A, const float* __restrict__ b2A,
    const float* __restrict__ W2E, const float* __restrict__ b2E,
    const float* __restrict__ W2L, const float* __restrict__ b2L,
    const float* __restrict__ merger, float* __restrict__ W2r,
    int* __restrict__ Zcnt)
{
    int idx = blockIdx.x * 256 + threadIdx.x;      // one float4 per thread
    if (idx < 384) Zcnt[idx] = 0;                  // counters for K2 epilogue
    if (idx >= W2R_F4_TOT) return;
    int half = idx / (NETS*HG*64);
    int rem  = idx - half * (NETS*HG*64);
    int net  = rem / (HG*64);
    rem     -= net * (HG*64);
    int g4   = rem >> 6;
    int hid  = rem & 63;

    float m0 = merger[hid], m1 = merger[64+hid], m2 = merger[128+hid], m3 = merger[192+hid];
    float mx = fmaxf(fmaxf(m0, m1), fmaxf(m2, m3));
    float e0 = expf(m0-mx), e1 = expf(m1-mx), e2 = expf(m2-mx), e3 = expf(m3-mx);
    float inv = 1.0f / (e0+e1+e2+e3);
    float w0 = e0*inv, w1 = e1*inv, w2 = e2*inv, w3 = e3*inv;

    const float* W2 = (net==0) ? W2A : ((net==1) ? W2E : W2L);
    const float* b2 = (net==0) ? b2A : ((net==1) ? b2E : b2L);

    float4 v;
    float* vp = &v.x;
    #pragma unroll
    for (int r = 0; r < 4; ++r) {
        int row = g4*4 + r;
        float val = 0.0f;
        if (row < 325) {
            const float* src;
            int kk;
            if (row < 320) { kk = half*5 + (row >> 6); int h = row & 63; src = W2 + h*2560; }
            else           { kk = half*5 + (row - 320);                  src = b2; }
            int col = (kk < 9) ? kk*256 : 2304;
            val = w0*src[col+hid] + w1*src[col+64+hid] + w2*src[col+128+hid] + w3*src[col+192+hid];
        }
        vp[r] = val;
    }
    ((float4*)W2r)[idx] = v;
}

// ---------------------------------------------------------------------------
// K2: 768 blocks (agent = blk>>1, half = blk&1) x 256 thr, 3 blocks/CU.
// Builds its kk-half of U (layer-1 weights staged in LDS), contracts against
// its half of W2r (global wk prefetch only), writes partial Z, and the
// LAST block per agent runs the fc1/fc2 epilogue inline (last-block pattern).
// ---------------------------------------------------------------------------
__global__ __launch_bounds__(256, 3) void half_kernel(
    const float* __restrict__ inputs, const float* __restrict__ actions,
    const float* __restrict__ W1A, const float* __restrict__ b1A,
    const float* __restrict__ W1E, const float* __restrict__ b1E,
    const float* __restrict__ W1L, const float* __restrict__ b1L,
    const float* __restrict__ W2r, float* __restrict__ Zpart,
    int* __restrict__ Zcnt,
    const float* __restrict__ fc1w, const float* __restrict__ fc1b,
    const float* __restrict__ fc2w, const float* __restrict__ fc2b,
    float* __restrict__ out_q, float* __restrict__ out_x)
{
    __shared__ float sOb[32];
    __shared__ float sSt[8], sCt[8], sSa[8], sCa[8], sVx[8], sVy[8];
    __shared__ float sRbf[8][3];
    __shared__ float sAct[3];
    __shared__ float sF[64][10];
    __shared__ float sW1[NETS*640];                   // per net: [0..575]=W1 kk*64+h, [576..639]=b1
    __shared__ __align__(16) float sU[8 * JSTRIDE];   // 36,864 B; tail reused for sZp/sZ
    __shared__ float sRed[4];
    __shared__ int   sIsLast;

    const int tid   = threadIdx.x;
    const int agent = blockIdx.x >> 1;
    const int half  = blockIdx.x & 1;

    // ---- stage obs/action + layer-1 weights into LDS ----
    if (tid < 30) sOb[tid] = inputs[agent*30 + tid];
    if (tid == 30) sOb[30] = actions[agent*2 + 0];
    if (tid == 31) sOb[31] = actions[agent*2 + 1];
    for (int i = tid; i < 480; i += 256) {            // 480 float4 = 1920 floats
        int net = i / 160, r = i - net*160;
        const float* W1 = (net==0) ? W1A : ((net==1) ? W1E : W1L);
        const float* b1 = (net==0) ? b1A : ((net==1) ? b1E : b1L);
        const float4 v = (r < 144) ? ((const float4*)W1)[r] : ((const float4*)b1)[r-144];
        ((float4*)(sW1 + net*640))[r] = v;
    }
    __syncthreads();

    if (tid < 8) {
        int e = tid;
        float px, py, vx, vy;
        if (e < 2)      {           px = sOb[10+2*e]; py = sOb[11+2*e]; vx = sOb[20+2*e]; vy = sOb[21+2*e]; }
        else if (e < 5) { int t=e-2; px = sOb[14+2*t]; py = sOb[15+2*t]; vx = sOb[24+2*t]; vy = sOb[25+2*t]; }
        else            { int t=e-5; px = sOb[4+2*t];  py = sOb[5+2*t];  vx = -sOb[0];     vy = -sOb[1]; }
        float d  = sqrtf(px*px + py*py);
        sSt[e] = py / (d + EPS);
        sCt[e] = px / (d + EPS);
        float vn = sqrtf(vx*vx + vy*vy);
        sSa[e] = vy / (vn + EPS);
        sCa[e] = vx / (vn + EPS);
        sVx[e] = vx; sVy[e] = vy;
        sRbf[e][0] = expf(-0.02f * d * d);
        float d5  = d - 5.0f;  sRbf[e][1] = expf(-0.02f * d5  * d5);
        float d10 = d - 10.0f; sRbf[e][2] = expf(-0.02f * d10 * d10);
    }
    if (tid == 8) {
        float ax = sOb[30], ay = sOb[31];
        float an = sqrtf(ax*ax + ay*ay);
        sAct[0] = an;
        sAct[1] = ay / (an + EPS);
        sAct[2] = ax / (an + EPS);
    }
    __syncthreads();

    if (tid < 64) {
        int p = tid, j = p >> 3, k = p & 7;
        sF[p][0] = sRbf[k][0];
        sF[p][1] = sRbf[k][1];
        sF[p][2] = sRbf[k][2];
        sF[p][3] = sSt[k]*sCt[j] - sCt[k]*sSt[j];
        sF[p][4] = sCt[k]*sCt[j] + sSt[k]*sSt[j];
        sF[p][5] = sSa[k]*sCt[j] - sCa[k]*sSt[j];
        sF[p][6] = sCa[k]*sCt[j] + sSa[k]*sSt[j];
        sF[p][7] = sVx[k] - sVx[j];
        sF[p][8] = sVy[k] - sVy[j];
        sF[p][9] = 1.0f;
    }
    __syncthreads();

    // ---- fused layer-1 + U build (single merged loop, all from LDS) ----
    // e<1536: main (j,net,h) triples -> rows kk_local*64+h, kk_local 0..4
    // e>=1536: rows 320..383 -> bias (r<5) or zero pad
    for (int e = tid; e < 3072; e += 256) {
        if (e < 1536) {
            int j = e / 192, rem = e - j*192;
            int net = rem >> 6, h = rem & 63;
            int ks = (net==0) ? 0 : ((net==1) ? 2 : 5);
            int kn = (net==0) ? 2 : 3;
            const float* w1 = sW1 + net*640;
            float v[5];
            #pragma unroll
            for (int c = 0; c < 5; ++c) v[c] = 0.0f;
            for (int q = 0; q < kn; ++q) {
                int p = j*8 + ks + q;
                float acc = w1[576 + h];
                #pragma unroll
                for (int kk = 0; kk < 9; ++kk) acc = fmaf(sF[p][kk], w1[kk*64 + h], acc);
                float H = (acc > 0.0f) ? acc : 0.01f*acc;
                #pragma unroll
                for (int c = 0; c < 5; ++c) v[c] = fmaf(H, sF[p][half*5 + c], v[c]);
            }
            float* dst = sU + (j*NETS + net)*HROWP + h;
            #pragma unroll
            for (int c = 0; c < 5; ++c) dst[c*64] = v[c];
        } else {
            int t = e - 1536;
            int j = t / 192, rem = t - j*192;
            int net = rem >> 6, r = rem & 63;
            float v = 0.0f;
            if (r < 5) {
                int kk = half*5 + r;
                int ks = (net==0) ? 0 : ((net==1) ? 2 : 5);
                int kn = (net==0) ? 2 : 3;
                for (int q = 0; q < kn; ++q) v += sF[j*8 + ks + q][kk];
            }
            sU[(j*NETS + net)*HROWP + 320 + r] = v;
        }
    }
    __syncthreads();

    // ---- contraction: lane=(q rows-slot, hh hid-base); acc[8j][4hid] ----
    float vr[8][4];      // q-reduced wave partials (valid on q==0 lanes)
    {
        const int lane = tid & 63, w = tid >> 6;
        const int q = lane >> 4, hh = lane & 15;
        const int base = w * GPW;
        float acc[8][4];
        #pragma unroll
        for (int j = 0; j < 8; ++j)
            #pragma unroll
            for (int k = 0; k < 4; ++k) acc[j][k] = 0.0f;

        const float4* Wbase = (const float4*)W2r + (size_t)half * (NETS*HG*64);
        float4 wk0, wk1, wk2, wk3;
        {   int g = base + q;
            const float4* wb = Wbase + g*64 + hh;
            wk0 = wb[0]; wk1 = wb[16]; wk2 = wb[32]; wk3 = wb[48]; }

        for (int it = 0; it < 18; ++it) {             // it = net*6 + u
            int net = it / 6, u = it - net*6;
            int g = base + u*4 + q;
            float4 nk0, nk1, nk2, nk3;
            if (it < 17) {
                int nit = it + 1;
                int nnet = nit / 6, nu_ = nit - nnet*6;
                int ng = base + nu_*4 + q;
                const float4* wb = Wbase + (nnet*HG + ng)*64 + hh;
                nk0 = wb[0]; nk1 = wb[16]; nk2 = wb[32]; nk3 = wb[48];
            }
            const float* Ub = sU + net*HROWP + g*4;
            #pragma unroll
            for (int j = 0; j < 8; ++j) {
                float4 uu = *(const float4*)(Ub + j*JSTRIDE);
                acc[j][0] = fmaf(uu.x,wk0.x, fmaf(uu.y,wk0.y, fmaf(uu.z,wk0.z, fmaf(uu.w,wk0.w, acc[j][0]))));
                acc[j][1] = fmaf(uu.x,wk1.x, fmaf(uu.y,wk1.y, fmaf(uu.z,wk1.z, fmaf(uu.w,wk1.w, acc[j][1]))));
                acc[j][2] = fmaf(uu.x,wk2.x, fmaf(uu.y,wk2.y, fmaf(uu.z,wk2.z, fmaf(uu.w,wk2.w, acc[j][2]))));
                acc[j][3] = fmaf(uu.x,wk3.x, fmaf(uu.y,wk3.y, fmaf(uu.z,wk3.z, fmaf(uu.w,wk3.w, acc[j][3]))));
            }
            wk0 = nk0; wk1 = nk1; wk2 = nk2; wk3 = nk3;
        }
        #pragma unroll
        for (int j = 0; j < 8; ++j)
            #pragma unroll
            for (int k = 0; k < 4; ++k) {
                float v = acc[j][k];
                v += __shfl_xor(v, 16);
                v += __shfl_xor(v, 32);
                vr[j][k] = v;
            }
    }
    __syncthreads();                     // all waves done reading sU
    // sZp aliases the start of sU (reads of sU are complete)
    {
        float* sZp = sU;                 // [w][j][64]
        const int lane = tid & 63, w = tid >> 6;
        const int q = lane >> 4, hh = lane & 15;
        if (q == 0) {
            #pragma unroll
            for (int j = 0; j < 8; ++j)
                #pragma unroll
                for (int k = 0; k < 4; ++k)
                    sZp[(w*8 + j)*64 + k*16 + hh] = vr[j][k];
        }
    }
    __syncthreads();
    {
        const float* sZp = sU;
        float* dst = Zpart + (size_t)agent*1024 + half*512;
        for (int o = tid; o < 512; o += 256)
            dst[o] = sZp[o] + sZp[512+o] + sZp[1024+o] + sZp[1536+o];
    }
    __threadfence();
    __syncthreads();
    if (tid == 0) {
        int old = atomicAdd(&Zcnt[agent], 1);
        sIsLast = (old == 1);
    }
    __syncthreads();
    if (!sIsLast) return;
    __threadfence();                     // acquire partner's Zpart writes

    // ---- fused epilogue (last block per agent only) ----
    float* sZ = sU + 2048;               // 512 floats, past the sZp region
    {
        const float* Zp = Zpart + (size_t)agent*1024;
        for (int o = tid; o < 512; o += 256) {
            float z = Zp[o] + Zp[512 + o];
            sZ[o] = (z > 0.0f) ? z : 0.0f;
        }
    }
    __syncthreads();
    {
        float an  = sAct[0], sb = sAct[1], cb = sAct[2];
        float anr = (an > 0.0f) ? an : 0.0f;
        float myq = 0.0f;
        #pragma unroll
        for (int i = 0; i < 2; ++i) {
            int o = i*256 + tid;
            int j = o >> 6, c = o & 63;
            float acc = fc1b[c];
            #pragma unroll 8
            for (int d = 0; d < 64; ++d)
                acc = fmaf(sZ[j*64 + d], fc1w[d*64 + c], acc);
            float aa0 = sb*sCt[j] - cb*sSt[j];
            float aa1 = cb*sCt[j] + sb*sSt[j];
            aa0 = (aa0 > 0.0f) ? aa0 : 0.0f;
            aa1 = (aa1 > 0.0f) ? aa1 : 0.0f;
            acc = fmaf(anr, fc1w[64*64 + c], acc);
            acc = fmaf(aa0, fc1w[65*64 + c], acc);
            acc = fmaf(aa1, fc1w[66*64 + c], acc);
            float x1 = (acc > 0.0f) ? acc : 0.0f;
            out_x[(agent*8 + j)*64 + c] = x1;
            myq = fmaf(x1, fc2w[c], myq);
        }
        for (int off = 32; off; off >>= 1) myq += __shfl_down(myq, off);
        int lane = tid & 63, w = tid >> 6;
        if (lane == 0) sRed[w] = myq;
        __syncthreads();
        if (tid == 0) out_q[agent] = (sRed[0] + sRed[1] + sRed[2] + sRed[3]) * 0.125f + fc2b[0];
    }
}

extern "C" void kernel_launch(void* const* d_in, const int* in_sizes, int n_in,
                              void* d_out, int out_size, void* d_ws, size_t ws_size,
                              hipStream_t stream) {
    const float* inputs  = (const float*)d_in[0];
    const float* actions = (const float*)d_in[2];
    const float* hA1_w = (const float*)d_in[3];  const float* hA1_b = (const float*)d_in[4];
    const float* hA2_w = (const float*)d_in[5];  const float* hA2_b = (const float*)d_in[6];
    const float* hE1_w = (const float*)d_in[7];  const float* hE1_b = (const float*)d_in[8];
    const float* hE2_w = (const float*)d_in[9];  const float* hE2_b = (const float*)d_in[10];
    const float* hL1_w = (const float*)d_in[11]; const float* hL1_b = (const float*)d_in[12];
    const float* hL2_w = (const float*)d_in[13]; const float* hL2_b = (const float*)d_in[14];
    const float* merger = (const float*)d_in[15];
    const float* fc1w = (const float*)d_in[16];  const float* fc1b = (const float*)d_in[17];
    const float* fc2w = (const float*)d_in[18];  const float* fc2b = (const float*)d_in[19];

    float* W2r   = (float*)d_ws;
    float* Zpart = (float*)((char*)d_ws + ZPART_OFF);
    int*   Zcnt  = (int*)  ((char*)d_ws + ZCNT_OFF);
    float* q     = (float*)d_out;
    float* x     = q + 384;

    prep_w2r<<<(W2R_F4_TOT + 255)/256, 256, 0, stream>>>(
        hA2_w, hA2_b, hE2_w, hE2_b, hL2_w, hL2_b, merger, W2r, Zcnt);
    half_kernel<<<768, 256, 0, stream>>>(
        inputs, actions, hA1_w, hA1_b, hE1_w, hE1_b, hL1_w, hL1_b,
        W2r, Zpart, Zcnt, fc1w, fc1b, fc2w, fc2b, q, x);
}

// Round 6
// 120.013 us; speedup vs baseline: 1.6499x; 1.6499x over previous
//
#include <hip/hip_runtime.h>
#include <math.h>

#define EPS 1e-7f
#define NETS 3
#define HROWP 384                 // padded rows per net per half (325 useful)
#define HG    (HROWP/4)           // 96 groups per net per half
#define GPW   (HG/4)              // 24 groups per wave per net
#define JSTRIDE (NETS*HROWP)      // 1152 floats between j's in sU
#define W2R_F4_TOT (2*NETS*HG*64) // 36864 float4s
#define ZPART_OFF 589824          // bytes: after W2r

// ---------------------------------------------------------------------------
// K1: head-reduced hyper-weights packed [half][net][g][hid][4rows].
// Row layout per (half,net): rows<320: kk_local*64+h (kk = half*5+kk_local);
// rows 320..324: b2 path; 325..383: zero pad.
// col(kk) = kk*256 for kk<9, 2304 for kk==9 (the "+b" einsum term, f'[9]=1).
// ---------------------------------------------------------------------------
__global__ __launch_bounds__(256) void prep_w2r(
    const float* __restrict__ W2A, const float* __restrict__ b2A,
    const float* __restrict__ W2E, const float* __restrict__ b2E,
    const float* __restrict__ W2L, const float* __restrict__ b2L,
    const float* __restrict__ merger, float* __restrict__ W2r)
{
    int idx = blockIdx.x * 256 + threadIdx.x;      // one float4 per thread
    if (idx >= W2R_F4_TOT) return;
    int half = idx / (NETS*HG*64);
    int rem  = idx - half * (NETS*HG*64);
    int net  = rem / (HG*64);
    rem     -= net * (HG*64);
    int g4   = rem >> 6;
    int hid  = rem & 63;

    float m0 = merger[hid], m1 = merger[64+hid], m2 = merger[128+hid], m3 = merger[192+hid];
    float mx = fmaxf(fmaxf(m0, m1), fmaxf(m2, m3));
    float e0 = expf(m0-mx), e1 = expf(m1-mx), e2 = expf(m2-mx), e3 = expf(m3-mx);
    float inv = 1.0f / (e0+e1+e2+e3);
    float w0 = e0*inv, w1 = e1*inv, w2 = e2*inv, w3 = e3*inv;

    const float* W2 = (net==0) ? W2A : ((net==1) ? W2E : W2L);
    const float* b2 = (net==0) ? b2A : ((net==1) ? b2E : b2L);

    float4 v;
    float* vp = &v.x;
    #pragma unroll
    for (int r = 0; r < 4; ++r) {
        int row = g4*4 + r;
        float val = 0.0f;
        if (row < 325) {
            const float* src;
            int kk;
            if (row < 320) { kk = half*5 + (row >> 6); int h = row & 63; src = W2 + h*2560; }
            else           { kk = half*5 + (row - 320);                  src = b2; }
            int col = (kk < 9) ? kk*256 : 2304;
            val = w0*src[col+hid] + w1*src[col+64+hid] + w2*src[col+128+hid] + w3*src[col+192+hid];
        }
        vp[r] = val;
    }
    ((float4*)W2r)[idx] = v;
}

// ---------------------------------------------------------------------------
// K2: 768 blocks (agent = blk>>1, half = blk&1) x 256 thr, 3 blocks/CU.
// U-build is wave-per-(j,net), lanes = h: W1 columns in registers (global,
// loaded once), f' rows via 3 broadcast ds_read_b128, stride-1 stores.
// Contraction: row-split across waves, global wk 1-deep prefetch.
// ---------------------------------------------------------------------------
__global__ __launch_bounds__(256, 3) void half_kernel(
    const float* __restrict__ inputs, const float* __restrict__ actions,
    const float* __restrict__ W1A, const float* __restrict__ b1A,
    const float* __restrict__ W1E, const float* __restrict__ b1E,
    const float* __restrict__ W1L, const float* __restrict__ b1L,
    const float* __restrict__ W2r, float* __restrict__ Zpart)
{
    __shared__ float sOb[32];
    __shared__ float sSt[8], sCt[8], sSa[8], sCa[8], sVx[8], sVy[8];
    __shared__ float sRbf[8][3];
    __shared__ __align__(16) float sF2[64][12];        // f' padded to 12
    __shared__ __align__(16) float sU[8 * JSTRIDE];    // 36,864 B; reused for sZp

    const int tid   = threadIdx.x;
    const int agent = blockIdx.x >> 1;
    const int half  = blockIdx.x & 1;
    const int lane  = tid & 63;
    const int w     = tid >> 6;

    // ---- preload W1 columns for h = lane into registers (global, coalesced) ----
    float w1r[3][9], b1r[3];
    {
        const float* Ws[3] = {W1A, W1E, W1L};
        const float* bs[3] = {b1A, b1E, b1L};
        #pragma unroll
        for (int net = 0; net < 3; ++net) {
            #pragma unroll
            for (int kk = 0; kk < 9; ++kk) w1r[net][kk] = Ws[net][kk*64 + lane];
            b1r[net] = bs[net][lane];
        }
    }

    // ---- stage obs/action ----
    if (tid < 30) sOb[tid] = inputs[agent*30 + tid];
    if (tid == 30) sOb[30] = actions[agent*2 + 0];
    if (tid == 31) sOb[31] = actions[agent*2 + 1];
    __syncthreads();

    if (tid < 8) {
        int e = tid;
        float px, py, vx, vy;
        if (e < 2)      {           px = sOb[10+2*e]; py = sOb[11+2*e]; vx = sOb[20+2*e]; vy = sOb[21+2*e]; }
        else if (e < 5) { int t=e-2; px = sOb[14+2*t]; py = sOb[15+2*t]; vx = sOb[24+2*t]; vy = sOb[25+2*t]; }
        else            { int t=e-5; px = sOb[4+2*t];  py = sOb[5+2*t];  vx = -sOb[0];     vy = -sOb[1]; }
        float d  = sqrtf(px*px + py*py);
        sSt[e] = py / (d + EPS);
        sCt[e] = px / (d + EPS);
        float vn = sqrtf(vx*vx + vy*vy);
        sSa[e] = vy / (vn + EPS);
        sCa[e] = vx / (vn + EPS);
        sVx[e] = vx; sVy[e] = vy;
        sRbf[e][0] = expf(-0.02f * d * d);
        float d5  = d - 5.0f;  sRbf[e][1] = expf(-0.02f * d5  * d5);
        float d10 = d - 10.0f; sRbf[e][2] = expf(-0.02f * d10 * d10);
    }
    __syncthreads();

    if (tid < 64) {
        int p = tid, j = p >> 3, k = p & 7;
        sF2[p][0] = sRbf[k][0];
        sF2[p][1] = sRbf[k][1];
        sF2[p][2] = sRbf[k][2];
        sF2[p][3] = sSt[k]*sCt[j] - sCt[k]*sSt[j];
        sF2[p][4] = sCt[k]*sCt[j] + sSt[k]*sSt[j];
        sF2[p][5] = sSa[k]*sCt[j] - sCa[k]*sSt[j];
        sF2[p][6] = sCa[k]*sCt[j] + sSa[k]*sSt[j];
        sF2[p][7] = sVx[k] - sVx[j];
        sF2[p][8] = sVy[k] - sVy[j];
        sF2[p][9] = 1.0f;
        sF2[p][10] = 0.0f;
        sF2[p][11] = 0.0f;
    }
    __syncthreads();

    // ---- U build: wave w handles (j = 2w+t, net), lanes = h ----
    {
        const int h = lane;
        #pragma unroll
        for (int t = 0; t < 2; ++t) {
            int j = 2*w + t;
            #pragma unroll
            for (int net = 0; net < NETS; ++net) {
                int ks = (net==0) ? 0 : ((net==1) ? 2 : 5);
                int kn = (net==0) ? 2 : 3;
                float v0=0.f,v1=0.f,v2=0.f,v3=0.f,v4=0.f;
                float gs0=0.f,gs1=0.f,gs2=0.f,gs3=0.f,gs4=0.f;
                for (int q = 0; q < kn; ++q) {
                    int p = j*8 + ks + q;                 // wave-uniform -> broadcast reads
                    float4 fa = *(const float4*)&sF2[p][0];
                    float4 fb = *(const float4*)&sF2[p][4];
                    float4 fc = *(const float4*)&sF2[p][8];
                    float acc = b1r[net];
                    acc = fmaf(fa.x, w1r[net][0], acc);
                    acc = fmaf(fa.y, w1r[net][1], acc);
                    acc = fmaf(fa.z, w1r[net][2], acc);
                    acc = fmaf(fa.w, w1r[net][3], acc);
                    acc = fmaf(fb.x, w1r[net][4], acc);
                    acc = fmaf(fb.y, w1r[net][5], acc);
                    acc = fmaf(fb.z, w1r[net][6], acc);
                    acc = fmaf(fb.w, w1r[net][7], acc);
                    acc = fmaf(fc.x, w1r[net][8], acc);
                    float H = (acc > 0.0f) ? acc : 0.01f*acc;
                    // g_c = f'[half*5 + c]
                    float g0 = half ? fb.y : fa.x;
                    float g1 = half ? fb.z : fa.y;
                    float g2 = half ? fb.w : fa.z;
                    float g3 = half ? fc.x : fa.w;
                    float g4 = half ? fc.y : fb.x;
                    v0 = fmaf(H, g0, v0);  gs0 += g0;
                    v1 = fmaf(H, g1, v1);  gs1 += g1;
                    v2 = fmaf(H, g2, v2);  gs2 += g2;
                    v3 = fmaf(H, g3, v3);  gs3 += g3;
                    v4 = fmaf(H, g4, v4);  gs4 += g4;
                }
                float* dst = sU + (j*NETS + net)*HROWP + h;
                dst[0]   = v0;
                dst[64]  = v1;
                dst[128] = v2;
                dst[192] = v3;
                dst[256] = v4;
                // bias rows 320..324 (h<5) + zero pad 325..383, one store
                float bv = 0.0f;
                bv = (h==0) ? gs0 : bv;
                bv = (h==1) ? gs1 : bv;
                bv = (h==2) ? gs2 : bv;
                bv = (h==3) ? gs3 : bv;
                bv = (h==4) ? gs4 : bv;
                dst[320 - h + h] = bv;            // placeholder avoided below
                sU[(j*NETS + net)*HROWP + 320 + h] = bv;
            }
        }
    }
    __syncthreads();

    // ---- contraction: lane=(q rows-slot, hh hid-base); acc[8j][4hid] ----
    float vr[8][4];
    {
        const int q = lane >> 4, hh = lane & 15;
        const int base = w * GPW;
        float acc[8][4];
        #pragma unroll
        for (int j = 0; j < 8; ++j)
            #pragma unroll
            for (int k = 0; k < 4; ++k) acc[j][k] = 0.0f;

        const float4* Wbase = (const float4*)W2r + (size_t)half * (NETS*HG*64);
        float4 wk0, wk1, wk2, wk3;
        {   int g = base + q;
            const float4* wb = Wbase + g*64 + hh;
            wk0 = wb[0]; wk1 = wb[16]; wk2 = wb[32]; wk3 = wb[48]; }

        for (int it = 0; it < 18; ++it) {             // it = net*6 + u
            int net = it / 6, u = it - net*6;
            int g = base + u*4 + q;
            float4 nk0, nk1, nk2, nk3;
            if (it < 17) {
                int nit = it + 1;
                int nnet = nit / 6, nu_ = nit - nnet*6;
                int ng = base + nu_*4 + q;
                const float4* wb = Wbase + (nnet*HG + ng)*64 + hh;
                nk0 = wb[0]; nk1 = wb[16]; nk2 = wb[32]; nk3 = wb[48];
            }
            const float* Ub = sU + net*HROWP + g*4;
            #pragma unroll
            for (int j = 0; j < 8; ++j) {
                float4 uu = *(const float4*)(Ub + j*JSTRIDE);
                acc[j][0] = fmaf(uu.x,wk0.x, fmaf(uu.y,wk0.y, fmaf(uu.z,wk0.z, fmaf(uu.w,wk0.w, acc[j][0]))));
                acc[j][1] = fmaf(uu.x,wk1.x, fmaf(uu.y,wk1.y, fmaf(uu.z,wk1.z, fmaf(uu.w,wk1.w, acc[j][1]))));
                acc[j][2] = fmaf(uu.x,wk2.x, fmaf(uu.y,wk2.y, fmaf(uu.z,wk2.z, fmaf(uu.w,wk2.w, acc[j][2]))));
                acc[j][3] = fmaf(uu.x,wk3.x, fmaf(uu.y,wk3.y, fmaf(uu.z,wk3.z, fmaf(uu.w,wk3.w, acc[j][3]))));
            }
            wk0 = nk0; wk1 = nk1; wk2 = nk2; wk3 = nk3;
        }
        #pragma unroll
        for (int j = 0; j < 8; ++j)
            #pragma unroll
            for (int k = 0; k < 4; ++k) {
                float v = acc[j][k];
                v += __shfl_xor(v, 16);
                v += __shfl_xor(v, 32);
                vr[j][k] = v;
            }
    }
    __syncthreads();                     // all waves done reading sU
    {                                    // sZp aliases sU
        float* sZp = sU;
        const int q = lane >> 4, hh = lane & 15;
        if (q == 0) {
            #pragma unroll
            for (int j = 0; j < 8; ++j)
                #pragma unroll
                for (int k = 0; k < 4; ++k)
                    sZp[(w*8 + j)*64 + k*16 + hh] = vr[j][k];
        }
    }
    __syncthreads();
    {
        const float* sZp = sU;
        float* dst = Zpart + (size_t)agent*1024 + half*512;
        for (int o = tid; o < 512; o += 256)
            dst[o] = sZp[o] + sZp[512+o] + sZp[1024+o] + sZp[1536+o];
    }
}

// ---------------------------------------------------------------------------
// K3: epilogue. One block per agent. Sums the two Z halves, relu, fc1/fc2.
// ---------------------------------------------------------------------------
__global__ __launch_bounds__(256) void epilogue_kernel(
    const float* __restrict__ inputs, const float* __restrict__ actions,
    const float* __restrict__ Zpart,
    const float* __restrict__ fc1w, const float* __restrict__ fc1b,
    const float* __restrict__ fc2w, const float* __restrict__ fc2b,
    float* __restrict__ out_q, float* __restrict__ out_x)
{
    __shared__ float sOb[32];
    __shared__ float sSt[8], sCt[8];
    __shared__ float sAct[3];
    __shared__ float sZ[8][64];
    __shared__ float sRed[4];

    const int tid   = threadIdx.x;
    const int agent = blockIdx.x;

    if (tid < 30) sOb[tid] = inputs[agent*30 + tid];
    if (tid == 30) sOb[30] = actions[agent*2 + 0];
    if (tid == 31) sOb[31] = actions[agent*2 + 1];
    __syncthreads();

    if (tid < 8) {
        int e = tid;
        float px, py;
        if (e < 2)      {           px = sOb[10+2*e]; py = sOb[11+2*e]; }
        else if (e < 5) { int t=e-2; px = sOb[14+2*t]; py = sOb[15+2*t]; }
        else            { int t=e-5; px = sOb[4+2*t];  py = sOb[5+2*t]; }
        float d = sqrtf(px*px + py*py);
        sSt[e] = py / (d + EPS);
        sCt[e] = px / (d + EPS);
    }
    if (tid == 8) {
        float ax = sOb[30], ay = sOb[31];
        float an = sqrtf(ax*ax + ay*ay);
        sAct[0] = an;
        sAct[1] = ay / (an + EPS);
        sAct[2] = ax / (an + EPS);
    }
    const float* Zp = Zpart + (size_t)agent*1024;
    for (int o = tid; o < 512; o += 256) {
        float z = Zp[o] + Zp[512 + o];
        ((float*)sZ)[o] = (z > 0.0f) ? z : 0.0f;
    }
    __syncthreads();

    float an  = sAct[0], sb = sAct[1], cb = sAct[2];
    float anr = (an > 0.0f) ? an : 0.0f;
    float myq = 0.0f;
    #pragma unroll
    for (int i = 0; i < 2; ++i) {
        int o = i*256 + tid;
        int j = o >> 6, c = o & 63;
        float acc = fc1b[c];
        #pragma unroll 8
        for (int d = 0; d < 64; ++d)
            acc = fmaf(sZ[j][d], fc1w[d*64 + c], acc);
        float aa0 = sb*sCt[j] - cb*sSt[j];
        float aa1 = cb*sCt[j] + sb*sSt[j];
        aa0 = (aa0 > 0.0f) ? aa0 : 0.0f;
        aa1 = (aa1 > 0.0f) ? aa1 : 0.0f;
        acc = fmaf(anr, fc1w[64*64 + c], acc);
        acc = fmaf(aa0, fc1w[65*64 + c], acc);
        acc = fmaf(aa1, fc1w[66*64 + c], acc);
        float x1 = (acc > 0.0f) ? acc : 0.0f;
        out_x[(agent*8 + j)*64 + c] = x1;
        myq = fmaf(x1, fc2w[c], myq);
    }
    for (int off = 32; off; off >>= 1) myq += __shfl_down(myq, off);
    int lane = tid & 63, w = tid >> 6;
    if (lane == 0) sRed[w] = myq;
    __syncthreads();
    if (tid == 0) out_q[agent] = (sRed[0] + sRed[1] + sRed[2] + sRed[3]) * 0.125f + fc2b[0];
}

extern "C" void kernel_launch(void* const* d_in, const int* in_sizes, int n_in,
                              void* d_out, int out_size, void* d_ws, size_t ws_size,
                              hipStream_t stream) {
    const float* inputs  = (const float*)d_in[0];
    const float* actions = (const float*)d_in[2];
    const float* hA1_w = (const float*)d_in[3];  const float* hA1_b = (const float*)d_in[4];
    const float* hA2_w = (const float*)d_in[5];  const float* hA2_b = (const float*)d_in[6];
    const float* hE1_w = (const float*)d_in[7];  const float* hE1_b = (const float*)d_in[8];
    const float* hE2_w = (const float*)d_in[9];  const float* hE2_b = (const float*)d_in[10];
    const float* hL1_w = (const float*)d_in[11]; const float* hL1_b = (const float*)d_in[12];
    const float* hL2_w = (const float*)d_in[13]; const float* hL2_b = (const float*)d_in[14];
    const float* merger = (const float*)d_in[15];
    const float* fc1w = (const float*)d_in[16];  const float* fc1b = (const float*)d_in[17];
    const float* fc2w = (const float*)d_in[18];  const float* fc2b = (const float*)d_in[19];

    float* W2r   = (float*)d_ws;
    float* Zpart = (float*)((char*)d_ws + ZPART_OFF);
    float* q     = (float*)d_out;
    float* x     = q + 384;

    prep_w2r<<<(W2R_F4_TOT + 255)/256, 256, 0, stream>>>(
        hA2_w, hA2_b, hE2_w, hE2_b, hL2_w, hL2_b, merger, W2r);
    half_kernel<<<768, 256, 0, stream>>>(
        inputs, actions, hA1_w, hA1_b, hE1_w, hE1_b, hL1_w, hL1_b, W2r, Zpart);
    epilogue_kernel<<<384, 256, 0, stream>>>(
        inputs, actions, Zpart, fc1w, fc1b, fc2w, fc2b, q, x);
}